// Round 1
// baseline (19039.275 us; speedup 1.0000x reference)
//
#include <hip/hip_runtime.h>

// ============================================================================
// AttnDecoderRNN round 6: latency-bound -> restructure to 2 phases / 2 barriers
// over a 64-block grid (was 3 barriers / 256 blocks).
//  - ATTN phase: 1 block per batch b: scores (lane-per-s vs transposed keys),
//    softmax, ctx — all block-local.  Writes ctx (bf16) + attn row.
//  - MAT phase: 8 persistent blocks, block m owns h-cols [64m,64m+64).
//    h slice lives in LDS forever.  gi = W_ih.ctx full-K MFMA; GRU local;
//    partial-K (K=64) MFMA contributions of q_{t+1}, gh_{t+1}, logits_t
//    accumulated with f32 atomicAdd (LLC).  No h round trips at all.
//  - single-level 64-arrival barrier (1 counter + 1 flag line).
//  - keys stored transposed [b][h][s] as Ek=exp(2*key) bf16 (same score trick).
// ============================================================================

typedef short s8v __attribute__((ext_vector_type(8)));
typedef float f4v __attribute__((ext_vector_type(4)));
typedef float f2v __attribute__((ext_vector_type(2)));

// ws byte offsets
#define OFF_BAR   0u
#define OFF_Q     4096u        // 64*512 f32 (atomic-accumulated q, no bias)
#define OFF_GH    135168u      // 2 bufs * 64*1536 f32 (atomic-accumulated gh)
#define OFF_CTX   921600u      // 64*512 bf16
#define OFF_WA    987136u      // 512*512 bf16
#define OFF_WHH   1511424u     // 1536*512 bf16
#define OFF_WIH   3084288u     // 1536*512 bf16
#define OFF_WOUT  4657152u     // 512*512 bf16
#define OFF_KEYS  5181440u     // 64*512*256 bf16, TRANSPOSED [b][h][s]
#define OFF_ENC8  21958656u    // 64*256*512 fp8
#define WS_FULL   30347264u
#define MEMSET_BYTES 921600u   // bar + q + both gh bufs

// d_out offsets (in floats)
#define OUT_LOGITS 0u
#define OUT_HFIN   8388608u
#define OUT_ATTN   8421376u

__device__ __forceinline__ unsigned short f2bf(float f) {
  union { float f; unsigned u; } a; a.f = f;
  unsigned r = a.u + 0x7fffu + ((a.u >> 16) & 1u);
  return (unsigned short)(r >> 16);
}
__device__ __forceinline__ float bf2f(unsigned short h) {
  union { unsigned u; float f; } a; a.u = (unsigned)h << 16; return a.f;
}
__device__ __forceinline__ float cload(const float* p) {
  return __hip_atomic_load(p, __ATOMIC_RELAXED, __HIP_MEMORY_SCOPE_AGENT);
}
__device__ __forceinline__ void cstore(float* p, float v) {
  __hip_atomic_store(p, v, __ATOMIC_RELAXED, __HIP_MEMORY_SCOPE_AGENT);
}
__device__ __forceinline__ void cstoreu(unsigned* p, unsigned v) {
  __hip_atomic_store(p, v, __ATOMIC_RELAXED, __HIP_MEMORY_SCOPE_AGENT);
}
__device__ __forceinline__ unsigned long long cload64(const unsigned long long* p) {
  return __hip_atomic_load(p, __ATOMIC_RELAXED, __HIP_MEMORY_SCOPE_AGENT);
}
__device__ __forceinline__ float sigm(float x) {
  return __builtin_amdgcn_rcpf(1.f + __expf(-x));
}
__device__ __forceinline__ float tanh2(float x) {
  return 1.f - 2.f * __builtin_amdgcn_rcpf(1.f + __expf(x + x));
}
__device__ __forceinline__ f4v mfma16(s8v a, s8v b, f4v c) {
  return __builtin_amdgcn_mfma_f32_16x16x32_bf16(a, b, c, 0, 0, 0);
}

// single-level 64-block barrier: counter @bar[0], flag @bar[16] (separate line)
__device__ __forceinline__ void gbar(unsigned* bar, unsigned& gen) {
  asm volatile("s_waitcnt vmcnt(0) lgkmcnt(0)" ::: "memory");
  __syncthreads();
  if (threadIdx.x == 0) {
    __atomic_signal_fence(__ATOMIC_SEQ_CST);
    gen++;
    unsigned old = __hip_atomic_fetch_add(bar, 1u, __ATOMIC_RELAXED,
                                          __HIP_MEMORY_SCOPE_AGENT);
    if (old == gen * 64u - 1u)
      __hip_atomic_store(bar + 16, gen, __ATOMIC_RELAXED,
                         __HIP_MEMORY_SCOPE_AGENT);
    while (__hip_atomic_load(bar + 16, __ATOMIC_RELAXED,
                             __HIP_MEMORY_SCOPE_AGENT) < gen)
      __builtin_amdgcn_s_sleep(1);
    __atomic_signal_fence(__ATOMIC_SEQ_CST);
  }
  __syncthreads();
}

// ---------------------------------------------------------------------------
__global__ void __launch_bounds__(256) prep_kernel(
    const float* __restrict__ Wa, const float* __restrict__ Whh,
    const float* __restrict__ Wih, const float* __restrict__ Wout,
    const float* __restrict__ enc,
    unsigned short* __restrict__ wa_b, unsigned short* __restrict__ whh_b,
    unsigned short* __restrict__ wih_b, unsigned short* __restrict__ wout_b,
    unsigned char* __restrict__ enc8, int use_enc8) {
  const size_t gid = (size_t)blockIdx.x * 256 + threadIdx.x;
  const size_t stride = (size_t)gridDim.x * 256;
  for (size_t i = gid; i < 2097152u; i += stride) {
    float v; unsigned short* d;
    if (i < 262144u)       { v = Wa[i];             d = wa_b + i; }
    else if (i < 1048576u) { v = Whh[i - 262144u];  d = whh_b + (i - 262144u); }
    else if (i < 1835008u) { v = Wih[i - 1048576u]; d = wih_b + (i - 1048576u); }
    else                   { v = Wout[i - 1835008u];d = wout_b + (i - 1835008u); }
    *d = f2bf(v);
  }
  if (use_enc8) {
    for (size_t j = gid; j < 4194304u; j += stride) {
      float2 e = ((const float2*)enc)[j];
      int pk = __builtin_amdgcn_cvt_pk_fp8_f32(e.x, e.y, 0, false);
      ((unsigned short*)enc8)[j] = (unsigned short)(pk & 0xffff);
    }
  }
}

// ---------------------------------------------------------------------------
// keysT[b][h][s] = exp(2*(enc[b,s]·Ua[h] + bu[h]))  (bf16, transposed store)
// ---------------------------------------------------------------------------
__global__ void __launch_bounds__(256) keys_kernel(
    const float* __restrict__ enc, const float* __restrict__ Ua,
    const float* __restrict__ bu, unsigned short* __restrict__ keysT) {
  const int tid = threadIdx.x;
  const int w = tid >> 6, lane = tid & 63, ln = lane & 15, kq = lane >> 4;
  const int mb = blockIdx.x >> 3, nb = blockIdx.x & 7;
  const int mrow = mb * 64 + w * 16 + ln;
  f4v acc[4] = {{0,0,0,0},{0,0,0,0},{0,0,0,0},{0,0,0,0}};
  for (int ks = 0; ks < 16; ++ks) {
    const float* ap = enc + (size_t)mrow * 512 + ks * 32 + kq * 8;
    s8v af;
#pragma unroll
    for (int j = 0; j < 8; ++j) af[j] = (short)f2bf(ap[j]);
#pragma unroll
    for (int nt = 0; nt < 4; ++nt) {
      int n = nb * 64 + nt * 16 + ln;
      const float* up = Ua + (size_t)n * 512 + ks * 32 + kq * 8;
      s8v bf;
#pragma unroll
      for (int j = 0; j < 8; ++j) bf[j] = (short)f2bf(up[j]);
      acc[nt] = mfma16(af, bf, acc[nt]);
    }
  }
#pragma unroll
  for (int nt = 0; nt < 4; ++nt) {
    int n = nb * 64 + nt * 16 + ln;
    float bias = bu[n];
#pragma unroll
    for (int r = 0; r < 4; ++r) {
      int gm = mb * 64 + w * 16 + kq * 4 + r;
      int bb = gm >> 8, ss = gm & 255;
      keysT[(size_t)bb * 131072u + (size_t)n * 256 + ss] =
          f2bf(__expf(2.f * (acc[nt][r] + bias)));
    }
  }
}

// ---------------------------------------------------------------------------
// persistent decoder: 64 blocks x 512 threads
// ---------------------------------------------------------------------------
__global__ void __launch_bounds__(512) decoder_kernel(
    const float* __restrict__ enc, const float* __restrict__ ba_,
    const float* __restrict__ va_, const float* __restrict__ bih_,
    const float* __restrict__ bhh_, const float* __restrict__ bout_,
    const unsigned short* __restrict__ wa_b, const unsigned short* __restrict__ whh_b,
    const unsigned short* __restrict__ wih_b, const unsigned short* __restrict__ wout_b,
    const unsigned short* __restrict__ keysT, const unsigned char* __restrict__ enc8,
    unsigned* __restrict__ bar, float* __restrict__ qbuf,
    float* __restrict__ ghsum, unsigned short* __restrict__ ctxg,
    float* __restrict__ out, int use_enc8) {
  const int bid = blockIdx.x, tid = threadIdx.x;
  const int w = tid >> 6, lane = tid & 63, ln = lane & 15, kq = lane >> 4;
  const int ab = (bid & 7) * 8 + (bid >> 3);   // ATTN batch (XCD-grouped)

  float* logits = out + OUT_LOGITS;
  float* hfin   = out + OUT_HFIN;
  float* attn   = out + OUT_ATTN;

  __shared__ float2 evL[512];                  // {Eq[h], va[h]}
  __shared__ float swL[256];
  __shared__ float ZpL[8];
  __shared__ float cpart[2][256][2];
  __shared__ float hof[64][65];                // h slice (f32), MAT-persistent
  __shared__ unsigned short hT[64][72];        // h slice bf16 (padded rows)

  unsigned gen = 0;
  const float va_r = va_[tid];
  const float ba_r = ba_[tid];

  for (int i = tid; i < 64 * 65; i += 512) ((float*)hof)[i] = 0.f;
  // vasum
  float vs = va_r;
#pragma unroll
  for (int off = 32; off > 0; off >>= 1) vs += __shfl_xor(vs, off, 64);
  if (lane == 0) ZpL[w] = vs;
  __syncthreads();
  float vasum = 0.f;
#pragma unroll
  for (int l = 0; l < 8; ++l) vasum += ZpL[l];
  __syncthreads();

  // MAT constants (block m owns h-cols [64m, 64m+64))
  const int m = bid;
  const int wm = w >> 2, ct = w & 3;
  const int cl = ct * 16 + ln;                 // local col 0..63
  float bihv[3] = {0, 0, 0}, bhhv[3] = {0, 0, 0};
  if (bid < 8) {
#pragma unroll
    for (int g = 0; g < 3; ++g) {
      bihv[g] = bih_[g * 512 + m * 64 + cl];
      bhhv[g] = bhh_[g * 512 + m * 64 + cl];
    }
  }
  const unsigned short* kb = keysT + (size_t)ab * 131072u;
  const unsigned char* e8p = enc8 + (size_t)ab * 131072u;

#pragma clang loop unroll(disable)
  for (int t = 0; t < 256; ++t) {
    // ================= ATTN phase (all 64 blocks, one batch each) ==========
    {
      float qv = cload(qbuf + (size_t)ab * 512 + tid);
      cstore(qbuf + (size_t)ab * 512 + tid, 0.f);      // re-zero for t+1
      float2 ev; ev.x = __expf(2.f * (qv + ba_r)); ev.y = va_r;
      evL[tid] = ev;
      float* gz = ghsum + ((t + 1) & 1) * 98304u + bid * 1536;
      cstore(gz + tid, 0.f); cstore(gz + 512 + tid, 0.f);
      cstore(gz + 1024 + tid, 0.f);                    // zero gh buf for t+1
    }
    __syncthreads();
    {
      const int s = w * 32 + (lane & 31);
      const int h0 = (lane >> 5) * 256;
      const unsigned short* kp = kb + (size_t)h0 * 256 + s;
      float a2 = 0.f;
#pragma unroll 8
      for (int h = 0; h < 256; ++h) {
        float2 ev = evL[h0 + h];
        float Ek = bf2f(kp[(size_t)h * 256]);
        a2 += ev.y * __builtin_amdgcn_rcpf(1.f + ev.x * Ek);
      }
      a2 += __shfl_xor(a2, 32, 64);
      float wt = __expf(vasum - 2.f * a2);
      float zp = wt;
#pragma unroll
      for (int off = 16; off > 0; off >>= 1) zp += __shfl_xor(zp, off, 64);
      if (lane < 32) { swL[s] = wt; if (lane == 0) ZpL[w] = zp; }
    }
    __syncthreads();
    float Z = 0.f;
#pragma unroll
    for (int l = 0; l < 8; ++l) Z += ZpL[l];
    float invZ = __builtin_amdgcn_rcpf(Z);
    {
      const int hp = tid & 255, sh = tid >> 8;
      const int s0 = sh * 128;
      float c0 = 0.f, c1 = 0.f;
      if (use_enc8) {
        const unsigned char* ep = e8p + (size_t)s0 * 512 + hp * 2;
#pragma unroll 8
        for (int i = 0; i < 128; ++i) {
          float wt = swL[s0 + i];
          unsigned short v8 = *(const unsigned short*)(ep + (size_t)i * 512);
          f2v ef = __builtin_amdgcn_cvt_pk_f32_fp8((int)v8, false);
          c0 += wt * ef[0]; c1 += wt * ef[1];
        }
      } else {
        const float2* ep = (const float2*)(enc + (size_t)(ab * 256 + s0) * 512) + hp;
#pragma unroll 8
        for (int i = 0; i < 128; ++i) {
          float wt = swL[s0 + i];
          float2 e = ep[(size_t)i * 256];
          c0 += wt * e.x; c1 += wt * e.y;
        }
      }
      cpart[sh][hp][0] = c0; cpart[sh][hp][1] = c1;
    }
    __syncthreads();
    if (tid < 256) {
      float cc0 = (cpart[0][tid][0] + cpart[1][tid][0]) * invZ;
      float cc1 = (cpart[0][tid][1] + cpart[1][tid][1]) * invZ;
      unsigned pk = (unsigned)f2bf(cc0) | ((unsigned)f2bf(cc1) << 16);
      cstoreu((unsigned*)ctxg + (size_t)ab * 256 + tid, pk);
      attn[(size_t)ab * 65536 + (size_t)t * 256 + tid] = swL[tid] * invZ;
    }
    gbar(bar, gen);

    // ================= MAT phase (blocks 0..7) =============================
    if (bid < 8) {
      // gh (complete, accumulated by MAT_{t-1}) gathered in frag layout
      const float* ghp = ghsum + (t & 1) * 98304u;
      float ghv[3][2][4];
#pragma unroll
      for (int g = 0; g < 3; ++g)
#pragma unroll
        for (int mi = 0; mi < 2; ++mi)
#pragma unroll
          for (int r = 0; r < 4; ++r) {
            int bb = (2 * wm + mi) * 16 + kq * 4 + r;
            ghv[g][mi][r] = cload(ghp + (size_t)bb * 1536 + g * 512 + m * 64 + cl);
          }
      // gi = W_ih . ctx  (full K=512), wave (wm,ct): 3 gates x 2 Mtiles
      f4v acc[3][2];
#pragma unroll
      for (int g = 0; g < 3; ++g)
#pragma unroll
        for (int mi = 0; mi < 2; ++mi) acc[g][mi] = (f4v){0.f, 0.f, 0.f, 0.f};
      const unsigned long long* ca0 =
          (const unsigned long long*)ctxg + (size_t)(2 * wm * 16 + ln) * 128;
      const unsigned long long* ca1 = ca0 + 2048;   // +16 rows
      const s8v* wB[3];
#pragma unroll
      for (int g = 0; g < 3; ++g)
        wB[g] = (const s8v*)(wih_b + (size_t)(g * 512 + m * 64 + cl) * 512);
#pragma unroll 4
      for (int kt = 0; kt < 16; ++kt) {
        union { unsigned long long u[2]; s8v v; } a0u, a1u;
        a0u.u[0] = cload64(ca0 + kt * 8 + kq * 2);
        a0u.u[1] = cload64(ca0 + kt * 8 + kq * 2 + 1);
        a1u.u[0] = cload64(ca1 + kt * 8 + kq * 2);
        a1u.u[1] = cload64(ca1 + kt * 8 + kq * 2 + 1);
#pragma unroll
        for (int g = 0; g < 3; ++g) {
          s8v bf = wB[g][kt * 4 + kq];
          acc[g][0] = mfma16(a0u.v, bf, acc[g][0]);
          acc[g][1] = mfma16(a1u.v, bf, acc[g][1]);
        }
      }
      // GRU (h slice is LDS-persistent; each (b,c) owned by one lane forever)
#pragma unroll
      for (int mi = 0; mi < 2; ++mi)
#pragma unroll
        for (int r = 0; r < 4; ++r) {
          int bb = (2 * wm + mi) * 16 + kq * 4 + r;
          float rr = sigm(acc[0][mi][r] + bihv[0] + ghv[0][mi][r] + bhhv[0]);
          float zz = sigm(acc[1][mi][r] + bihv[1] + ghv[1][mi][r] + bhhv[1]);
          float nn = tanh2(acc[2][mi][r] + bihv[2] + rr * (ghv[2][mi][r] + bhhv[2]));
          float ho = hof[bb][cl];
          float hn = (1.f - zz) * nn + zz * ho;
          hof[bb][cl] = hn;
          hT[bb][cl] = f2bf(hn);
          if (t == 255) hfin[(size_t)bb * 512 + m * 64 + cl] = hn;
        }
      __syncthreads();
      // partial-K (K=64) contributions: q_{t+1} | gh_{t+1} | logits_t
      s8v af[2][4];
#pragma unroll
      for (int mt = 0; mt < 4; ++mt)
#pragma unroll
        for (int k2 = 0; k2 < 2; ++k2)
          af[k2][mt] = *(const s8v*)&hT[mt * 16 + ln][k2 * 32 + kq * 8];
      float* ghn = ghsum + ((t + 1) & 1) * 98304u;
#pragma clang loop unroll(disable)
      for (int i = 0; i < 20; ++i) {
        int nt = w + i * 8;                      // wave-uniform
        const unsigned short* wsrc; float* dst; int rs;
        if (nt < 32)       { int col = nt * 16 + ln;
          wsrc = wa_b + (size_t)col * 512; dst = qbuf + col; rs = 512; }
        else if (nt < 128) { int col = (nt - 32) * 16 + ln;
          wsrc = whh_b + (size_t)col * 512; dst = ghn + col; rs = 1536; }
        else               { int col = (nt - 128) * 16 + ln;
          wsrc = wout_b + (size_t)col * 512;
          dst = logits + (size_t)t * 32768 + col; rs = 512; }
        s8v b0 = ((const s8v*)wsrc)[m * 8 + kq];
        s8v b1 = ((const s8v*)wsrc)[m * 8 + 4 + kq];
#pragma unroll
        for (int mt = 0; mt < 4; ++mt) {
          f4v a4 = {0.f, 0.f, 0.f, 0.f};
          a4 = mfma16(af[0][mt], b0, a4);
          a4 = mfma16(af[1][mt], b1, a4);
#pragma unroll
          for (int r = 0; r < 4; ++r)
            atomicAdd(dst + (size_t)(mt * 16 + kq * 4 + r) * rs, a4[r]);
        }
      }
    }
    gbar(bar, gen);
  }

  // -------- final: +bout, log_softmax (logits were atomic-written -> cload) --
  float bo[8];
#pragma unroll
  for (int j = 0; j < 8; ++j) bo[j] = bout_[lane * 8 + j];
#pragma clang loop unroll(disable)
  for (int i = 0; i < 32; ++i) {
    int row = bid * 256 + w * 32 + i;
    const unsigned long long* xr64 =
        (const unsigned long long*)(logits + (size_t)row * 512) + lane * 4;
    unsigned long long t4[4];
#pragma unroll
    for (int j = 0; j < 4; ++j) t4[j] = cload64(xr64 + j);
    union { unsigned long long u[4]; float f[8]; } xu;
#pragma unroll
    for (int j = 0; j < 4; ++j) xu.u[j] = t4[j];
    float x[8];
#pragma unroll
    for (int j = 0; j < 8; ++j) x[j] = xu.f[j] + bo[j];
    float mx = x[0];
#pragma unroll
    for (int j = 1; j < 8; ++j) mx = fmaxf(mx, x[j]);
#pragma unroll
    for (int off = 32; off > 0; off >>= 1) mx = fmaxf(mx, __shfl_xor(mx, off, 64));
    float sm = 0.f;
#pragma unroll
    for (int j = 0; j < 8; ++j) sm += __expf(x[j] - mx);
#pragma unroll
    for (int off = 32; off > 0; off >>= 1) sm += __shfl_xor(sm, off, 64);
    float lse = mx + __logf(sm);
    float* xw = logits + (size_t)row * 512 + lane * 8;
    f4v o0, o1;
#pragma unroll
    for (int j = 0; j < 4; ++j) { o0[j] = x[j] - lse; o1[j] = x[4 + j] - lse; }
    ((f4v*)xw)[0] = o0;
    ((f4v*)xw)[1] = o1;
  }
}

// ---------------------------------------------------------------------------
extern "C" void kernel_launch(void* const* d_in, const int* in_sizes, int n_in,
                              void* d_out, int out_size, void* d_ws, size_t ws_size,
                              hipStream_t stream) {
  const float* enc  = (const float*)d_in[0];
  const float* Wa   = (const float*)d_in[1];
  const float* ba   = (const float*)d_in[2];
  const float* Ua   = (const float*)d_in[3];
  const float* bu   = (const float*)d_in[4];
  const float* Va   = (const float*)d_in[5];
  // d_in[6] = bv : softmax-invariant, unused
  const float* Wih  = (const float*)d_in[7];
  const float* bih  = (const float*)d_in[8];
  const float* Whh  = (const float*)d_in[9];
  const float* bhh  = (const float*)d_in[10];
  const float* Wout = (const float*)d_in[11];
  const float* bout = (const float*)d_in[12];
  (void)in_sizes; (void)n_in; (void)out_size;

  char* ws = (char*)d_ws;
  unsigned*       bar    = (unsigned*)(ws + OFF_BAR);
  float*          qbuf   = (float*)(ws + OFF_Q);
  float*          ghsum  = (float*)(ws + OFF_GH);
  unsigned short* ctxg   = (unsigned short*)(ws + OFF_CTX);
  unsigned short* wa_b   = (unsigned short*)(ws + OFF_WA);
  unsigned short* whh_b  = (unsigned short*)(ws + OFF_WHH);
  unsigned short* wih_b  = (unsigned short*)(ws + OFF_WIH);
  unsigned short* wout_b = (unsigned short*)(ws + OFF_WOUT);
  unsigned short* keysT  = (unsigned short*)(ws + OFF_KEYS);
  unsigned char*  enc8   = (unsigned char*)(ws + OFF_ENC8);
  int use_enc8 = (ws_size >= (size_t)WS_FULL) ? 1 : 0;

  hipMemsetAsync(d_ws, 0, MEMSET_BYTES, stream);       // bar + q + gh bufs
  hipMemsetAsync(d_out, 0, 33554432u, stream);         // logits f32 accum = 0
  prep_kernel<<<1024, 256, 0, stream>>>(Wa, Whh, Wih, Wout, enc,
                                        wa_b, whh_b, wih_b, wout_b,
                                        enc8, use_enc8);
  keys_kernel<<<2048, 256, 0, stream>>>(enc, Ua, bu, keysT);
  decoder_kernel<<<64, 512, 0, stream>>>(enc, ba, Va, bih, bhh, bout,
                                         wa_b, whh_b, wih_b, wout_b,
                                         keysT, enc8, bar, qbuf, ghsum, ctxg,
                                         (float*)d_out, use_enc8);
}